// Round 2
// baseline (529.048 us; speedup 1.0000x reference)
//
#include <hip/hip_runtime.h>
#include <hip/hip_bf16.h>

typedef __attribute__((ext_vector_type(8))) short short8;
typedef __attribute__((ext_vector_type(4))) float floatx4;

#define NB 65536   // batches
#define STS 18     // st row stride (elems): 16 p + 2 pad
#define WES 68     // wl e-stride (elems): 64 f + 4 pad
#define WBS 1092   // wl b-stride (elems): 16*68 + 4 pad

static __device__ __forceinline__ ushort f2bf(float x) {
  union { float f; unsigned u; } v; v.f = x;
  unsigned r = v.u + 0x7FFFu + ((v.u >> 16) & 1u);   // round-nearest-even
  return (ushort)(r >> 16);
}

// Build L = [inc(32 rows); I - d*inc^T inc (16 rows)] padded to K=32 with zeros,
// and Mt[e][g][f] = M[e][f][g] (g-major transpose so MFMA A-frags are contiguous).
// All inputs fp32; L/Mt stored bf16 for MFMA.
__global__ void sheaf_prep(const float* __restrict__ inc,
                           const float* __restrict__ M,
                           const float* __restrict__ damp,
                           ushort* __restrict__ Mt,
                           ushort* __restrict__ L) {
  const int bid = blockIdx.x, tid = threadIdx.x;
  if (bid < 32) {
    const float* Me = M + (bid << 12);
    ushort* Mte = Mt + (bid << 12);
    for (int i = tid; i < 4096; i += 256) {
      int g = i >> 6, f = i & 63;
      Mte[(g << 6) + f] = f2bf(Me[(f << 6) + g]);
    }
  } else {
    for (int i = tid; i < 1024; i += 256) {       // rows 0-31: incidence
      int e = i >> 5, col = i & 31;
      L[(e << 5) + col] = (col < 16) ? f2bf(inc[(e << 4) + col]) : (ushort)0;
    }
    float d = damp[0];
    int p = tid >> 4, q = tid & 15;               // rows 32-47: I - d*dTd (fp32 math)
    float s = 0.f;
    for (int e = 0; e < 32; ++e)
      s += inc[(e << 4) + p] * inc[(e << 4) + q];
    float a = ((p == q) ? 1.f : 0.f) - d * s;
    L[((32 + p) << 5) + q] = f2bf(a);
    L[((32 + p) << 5) + 16 + q] = (ushort)0;
  }
}

__global__ __launch_bounds__(256, 2) void sheaf_main(
    const float* __restrict__ S,
    const ushort* __restrict__ Mt,
    const ushort* __restrict__ L,
    float* __restrict__ out) {
  __shared__ ushort st[1024 * STS];   // [c=(b*64+f)][p]  36.9 KB, bf16
  __shared__ ushort wl[16 * WBS];     // [b][eloc][f]     34.9 KB, bf16
  __shared__ float h1s[4][16];

  const int tid = threadIdx.x;
  const int lane = tid & 63;
  const int w = tid >> 6;
  const int quad = lane >> 4;
  const int l15 = lane & 15;

  // ---- stage S tile (fp32 global, coalesced float4), convert bf16, transpose p innermost
  {
    const float4* gS = (const float4*)S + (size_t)blockIdx.x * 4096;
    #pragma unroll
    for (int i = 0; i < 16; ++i) {
      int v = tid + (i << 8);               // 0..4095 float4 index
      float4 raw = gS[v];
      int b = v >> 8, p = (v >> 4) & 15, fv = v & 15;
      int base = ((b << 6) + (fv << 2)) * STS + p;
      st[base]           = f2bf(raw.x);
      st[base + STS]     = f2bf(raw.y);
      st[base + 2 * STS] = f2bf(raw.z);
      st[base + 3 * STS] = f2bf(raw.w);
    }
  }

  // A-fragments of L (broadcast from L2): lane m=l15, k=quad*8+j
  short8 aL0 = *(const short8*)(L + (l15) * 32 + (quad << 3));        // e 0-15
  short8 aL1 = *(const short8*)(L + (16 + l15) * 32 + (quad << 3));   // e 16-31
  short8 aLp = *(const short8*)(L + (32 + l15) * 32 + (quad << 3));   // diffusion

  __syncthreads();

  float hp = 0.f;

  for (int ec = 0; ec < 2; ++ec) {
    short8 aE = ec ? aL1 : aL0;
    // ---- step-L: weighted for this e-chunk (+ diffused on first pass)
    for (int t = 0; t < 16; ++t) {
      int ctile = (w << 4) + t;
      int c = (ctile << 4) + l15;
      short8 bf;   // B[k=p][n=c]; quads 2,3 are K-padding -> 0
      {
        union { short8 v; unsigned wds[4]; } u;
        if (quad < 2) {
          const unsigned* row = (const unsigned*)(st + c * STS);
          int o = quad << 2;
          u.wds[0] = row[o];     u.wds[1] = row[o + 1];
          u.wds[2] = row[o + 2]; u.wds[3] = row[o + 3];
        } else {
          u.wds[0] = 0u; u.wds[1] = 0u; u.wds[2] = 0u; u.wds[3] = 0u;
        }
        bf = u.v;
      }
      floatx4 acc = {0.f, 0.f, 0.f, 0.f};
      acc = __builtin_amdgcn_mfma_f32_16x16x32_bf16(aE, bf, acc, 0, 0, 0);
      int b = c >> 6, f = c & 63;
      int wbase = b * WBS + f;
      #pragma unroll
      for (int r = 0; r < 4; ++r) {            // D row = e-local
        int eloc = (quad << 2) + r;
        wl[wbase + eloc * WES] = f2bf(acc[r]);
      }
      if (ec == 0) {
        floatx4 accD = {0.f, 0.f, 0.f, 0.f};
        accD = __builtin_amdgcn_mfma_f32_16x16x32_bf16(aLp, bf, accD, 0, 0, 0);
        size_t obase = ((size_t)blockIdx.x * 16 + (size_t)b) * 1024 + (size_t)f;
        #pragma unroll
        for (int r = 0; r < 4; ++r) {          // D row = p ; fp32 store
          int p = (quad << 2) + r;
          out[obase + p * 64] = accD[r];
        }
      }
    }
    __syncthreads();

    // ---- step-2: coboundary norms, 4 edges per wave
    #pragma unroll
    for (int i = 0; i < 4; ++i) {
      int eloc = (w << 2) + i;
      int e = (ec << 4) + eloc;
      const ushort* MtE = Mt + (e << 12);
      float ss = 0.f;
      #pragma unroll
      for (int gt = 0; gt < 4; ++gt) {
        floatx4 acc = {0.f, 0.f, 0.f, 0.f};
        #pragma unroll
        for (int ks = 0; ks < 2; ++ks) {
          // A[m=g][k=f] = Mt[e][g][f]  (16B contiguous per lane)
          short8 af = *(const short8*)(MtE + (((gt << 4) + l15) << 6) + (ks << 5) + (quad << 3));
          // B[k=f][n=b] = wl[b][eloc][f]
          union { short8 v; uint2 u2[2]; } ub;
          const uint2* pw = (const uint2*)(wl + l15 * WBS + eloc * WES + (ks << 5) + (quad << 3));
          ub.u2[0] = pw[0]; ub.u2[1] = pw[1];
          acc = __builtin_amdgcn_mfma_f32_16x16x32_bf16(af, ub.v, acc, 0, 0, 0);
        }
        ss += acc[0]*acc[0] + acc[1]*acc[1] + acc[2]*acc[2] + acc[3]*acc[3];
      }
      ss += __shfl_xor(ss, 16);   // sum over g across quads
      ss += __shfl_xor(ss, 32);
      hp += sqrtf(ss);            // per-(b=l15, e) L2 norm
    }
    __syncthreads();              // before next chunk overwrites wl
  }

  if (lane < 16) h1s[w][l15] = hp;
  __syncthreads();
  if (tid < 16) {
    float tsum = (h1s[0][tid] + h1s[1][tid] + h1s[2][tid] + h1s[3][tid]) * (1.f / 32.f);
    out[(size_t)NB * 1024 + (size_t)blockIdx.x * 16 + tid] = tsum;
  }
}

extern "C" void kernel_launch(void* const* d_in, const int* in_sizes, int n_in,
                              void* d_out, int out_size, void* d_ws, size_t ws_size,
                              hipStream_t stream) {
  const float* S   = (const float*)d_in[0];   // node_sections [B,P,F] fp32
  const float* inc = (const float*)d_in[1];   // incidence [E,P] fp32
  const float* M   = (const float*)d_in[2];   // sheaf_maps [E,F,F] fp32
  const float* dmp = (const float*)d_in[3];   // damping scalar fp32
  float* out = (float*)d_out;

  ushort* Mt = (ushort*)d_ws;        // 131072 bf16 elems (256 KB)
  ushort* L  = Mt + 131072;          // 48*32 = 1536 bf16 elems

  sheaf_prep<<<33, 256, 0, stream>>>(inc, M, dmp, Mt, L);
  sheaf_main<<<NB / 16, 256, 0, stream>>>(S, Mt, L, out);
}